// Round 9
// baseline (1649.841 us; speedup 1.0000x reference)
//
#include <hip/hip_runtime.h>
#include <math.h>

#define NNODE 65536
#define NEDGE 1048576
#define NGRAPH 128
#define NPG 512
#define EPG 8192
#define NBLK 512

typedef _Float16 f16x8 __attribute__((ext_vector_type(8)));
typedef _Float16 f16x4 __attribute__((ext_vector_type(4)));
typedef float f32x4 __attribute__((ext_vector_type(4)));

// ---- device-wide barrier (all NBLK blocks resident by construction) ----
__device__ __forceinline__ void grid_sync(int* bar) {
    __syncthreads();
    if (threadIdx.x == 0) {
        __threadfence();
        int g = __hip_atomic_load(bar + 1, __ATOMIC_RELAXED, __HIP_MEMORY_SCOPE_AGENT);
        int v = __hip_atomic_fetch_add(bar + 0, 1, __ATOMIC_ACQ_REL, __HIP_MEMORY_SCOPE_AGENT);
        if (v == NBLK - 1) {
            __hip_atomic_store(bar + 0, 0, __ATOMIC_RELAXED, __HIP_MEMORY_SCOPE_AGENT);
            __hip_atomic_fetch_add(bar + 1, 1, __ATOMIC_RELEASE, __HIP_MEMORY_SCOPE_AGENT);
        } else {
            int tries = 0;
            while (__hip_atomic_load(bar + 1, __ATOMIC_ACQUIRE, __HIP_MEMORY_SCOPE_AGENT) == g) {
                __builtin_amdgcn_s_sleep(16);
                if (++tries > (1 << 22)) break;   // safety valve, never hit if logic sound
            }
        }
        __threadfence();
    }
    __syncthreads();
}

#define CVT8(hi8, lo8, a0, a1, a2, a3, a4, a5, a6, a7)                         \
    {                                                                           \
        _Float16 q0 = (_Float16)a0, q1 = (_Float16)a1, q2 = (_Float16)a2,       \
                 q3 = (_Float16)a3, q4 = (_Float16)a4, q5 = (_Float16)a5,       \
                 q6 = (_Float16)a6, q7 = (_Float16)a7;                          \
        hi8 = (f16x8){q0, q1, q2, q3, q4, q5, q6, q7};                          \
        lo8 = (f16x8){(_Float16)((a0 - (float)q0) * 2048.f),                    \
                      (_Float16)((a1 - (float)q1) * 2048.f),                    \
                      (_Float16)((a2 - (float)q2) * 2048.f),                    \
                      (_Float16)((a3 - (float)q3) * 2048.f),                    \
                      (_Float16)((a4 - (float)q4) * 2048.f),                    \
                      (_Float16)((a5 - (float)q5) * 2048.f),                    \
                      (_Float16)((a6 - (float)q6) * 2048.f),                    \
                      (_Float16)((a7 - (float)q7) * 2048.f)};                   \
    }

__global__ __launch_bounds__(512, 4) void k_mega(
    const float* __restrict__ x_in, const float* __restrict__ inp_c,
    const int* __restrict__ srcE, const int* __restrict__ dstE,
    const float* __restrict__ W0, const float* __restrict__ W1, const float* __restrict__ W2,
    const float* __restrict__ b0, const float* __restrict__ b1, const float* __restrict__ b2,
    const float* __restrict__ p0, const float* __restrict__ p1, const float* __restrict__ p2,
    const float* __restrict__ We, const float* __restrict__ Wa, const float* __restrict__ ba,
    const float* __restrict__ Wb, const float* __restrict__ bb, const float* __restrict__ Wc,
    float* __restrict__ out,
    int* __restrict__ rp, int* __restrict__ csr, float* __restrict__ dinv,
    float* __restrict__ gate, float* __restrict__ score, int* __restrict__ alive,
    float* __restrict__ h, _Float16* __restrict__ xh, _Float16* __restrict__ xl,
    float* __restrict__ hg, _Float16* __restrict__ wfh, _Float16* __restrict__ wfl,
    int* __restrict__ bar) {

    __shared__ _Float16 sAH[128 * 72];   // 18 KB
    __shared__ _Float16 sAL[128 * 72];   // 18 KB
    __shared__ int s_cnt[512];
    __shared__ int s_tmp[512];
    __shared__ float2 s_nb[16][32];
    __shared__ unsigned s_hist[1024];
    __shared__ unsigned s_wsum[8];
    __shared__ float s_cand[512];
    __shared__ int s_ad[256];
    __shared__ float s_ag[256];
    __shared__ float s_red[1024];
    __shared__ int s_mnew[512];
    __shared__ int s_scnt;
    __shared__ unsigned s_ccnt;
    __shared__ unsigned s_tbb, s_tbab;
    __shared__ float s_thr;
    __shared__ float s_fus[320];
    __shared__ float s_h1[256];
    __shared__ float s_h2[128];

    int b = blockIdx.x, t = threadIdx.x;

    // ---------- phase 0: wconv (b<96) | csr+init (96<=b<224) | zero hg (224<=b<288) ----------
    if (b < 96) {
        int e = b * 512 + t;
        int l = e >> 14, e2 = e & 16383;
        const float* W = (l == 0) ? W0 : (l == 1) ? W1 : W2;
        int k = e2 >> 7, n = e2 & 127;
        float w = W[e2];
        _Float16 hi = (_Float16)w;
        _Float16 lo = (_Float16)((w - (float)hi) * 2048.0f);
        int nt = n >> 4, nn = n & 15, ks = k >> 5, quad = (k & 31) >> 3, j = k & 7;
        int off = l * 16384 + ((nt * 4 + ks) * 64 + (quad * 16 + nn)) * 8 + j;
        wfh[off] = hi;
        wfl[off] = lo;
    } else if (b < 224) {
        int g = b - 96;
        int nd = g * NPG + t;
        s_cnt[t] = 0;
        gate[nd] = 1.f;
        alive[nd] = nd;
        __syncthreads();
        int ebase = g * EPG;
        int dl[16];
        for (int i = 0; i < 16; ++i) {
            int e = ebase + t + i * 512;
            int d = dstE[e] - g * NPG;
            dl[i] = d;
            atomicAdd(&s_cnt[d], 1);
        }
        __syncthreads();
        int v = s_cnt[t], incl = v;
        dinv[nd] = rsqrtf(1.f + (float)v);
        for (int off = 1; off < 512; off <<= 1) {
            s_tmp[t] = incl; __syncthreads();
            if (t >= off) incl += s_tmp[t - off];
            __syncthreads();
        }
        int excl = incl - v;
        rp[nd] = ebase + excl;
        if (g == NGRAPH - 1 && t == 511) rp[NNODE] = NEDGE;
        __syncthreads();
        s_cnt[t] = excl;
        __syncthreads();
        for (int i = 0; i < 16; ++i) {
            int e = ebase + t + i * 512;
            int pos = atomicAdd(&s_cnt[dl[i]], 1);
            csr[ebase + pos] = srcE[e];
        }
    } else if (b < 288) {
        hg[(b - 224) * 512 + t] = 0.f;
    }
    grid_sync(bar);

    const int rowsA[3] = {65536, 32768, 16384};
    const int KinA[3] = {512, 256, 128};
    const float* biasA[3] = {b0, b1, b2};
    const float* pvA[3] = {p0, p1, p2};

    for (int l = 0; l < 3; ++l) {
        // ---------- gemm: h[alive] = gate * ((x hi/lo) @ W), split-f16 MFMA ----------
        int nbg = rowsA[l] >> 7;
        if (b < nbg) {
            int rowbase = b << 7;
            const _Float16* wfhL = wfh + l * 16384;
            const _Float16* wflL = wfl + l * 16384;
            int lane = t & 63, wv = t >> 6, quad = lane >> 4, mm = lane & 15;
            f32x4 accH[8], accM[8];
            for (int nt = 0; nt < 8; ++nt) {
                accH[nt] = (f32x4){0.f, 0.f, 0.f, 0.f};
                accM[nt] = (f32x4){0.f, 0.f, 0.f, 0.f};
            }
            for (int kh = 0; kh < 2; ++kh) {
                if (kh) __syncthreads();
                for (int pp = 0; pp < 2; ++pp) {
                    int c = t + pp * 512;          // 0..1023: 128 rows x 8 chunks
                    int r = c >> 3, ch = c & 7;
                    int node = alive[rowbase + r];
                    size_t src = (size_t)node * 128 + kh * 64 + ch * 8;
                    f16x8 hi8, lo8;
                    if (l == 0) {
                        float4 v0 = *(const float4*)(x_in + src);
                        float4 v1 = *(const float4*)(x_in + src + 4);
                        CVT8(hi8, lo8, v0.x, v0.y, v0.z, v0.w, v1.x, v1.y, v1.z, v1.w);
                    } else {
                        hi8 = *(const f16x8*)(xh + src);
                        lo8 = *(const f16x8*)(xl + src);
                    }
                    *(f16x8*)(sAH + r * 72 + ch * 8) = hi8;
                    *(f16x8*)(sAL + r * 72 + ch * 8) = lo8;
                }
                __syncthreads();
                for (int ksl = 0; ksl < 2; ++ksl) {
                    int row = wv * 16 + mm;
                    f16x8 Ah = *(const f16x8*)(sAH + row * 72 + ksl * 32 + quad * 8);
                    f16x8 Al = *(const f16x8*)(sAL + row * 72 + ksl * 32 + quad * 8);
                    for (int nt = 0; nt < 8; ++nt) {
                        int goff = ((nt * 4 + kh * 2 + ksl) * 64 + lane) * 8;
                        f16x8 Bh = *(const f16x8*)(wfhL + goff);
                        f16x8 Bl = *(const f16x8*)(wflL + goff);
                        accH[nt] = __builtin_amdgcn_mfma_f32_16x16x32_f16(Ah, Bh, accH[nt], 0, 0, 0);
                        accM[nt] = __builtin_amdgcn_mfma_f32_16x16x32_f16(Ah, Bl, accM[nt], 0, 0, 0);
                        accM[nt] = __builtin_amdgcn_mfma_f32_16x16x32_f16(Al, Bh, accM[nt], 0, 0, 0);
                    }
                }
            }
            // epilogue: C layout col=lane&15, row=quad*4+reg ; reuse lane/wv/quad/mm
            for (int i = 0; i < 4; ++i) {
                int rl = wv * 16 + quad * 4 + i;
                int node = alive[rowbase + rl];
                float gg = gate[node];
                float* hr = h + (size_t)node * 128 + mm;
                for (int nt = 0; nt < 8; ++nt)
                    hr[nt * 16] = gg * (accH[nt][i] + accM[nt][i] * (1.f / 2048.f));
            }
        }
        grid_sync(bar);

        // ---------- agg: half-wave per dst, 32-slot compacted prefetch, L2 gather ----------
        {
            int Kin = KinA[l];
            int g = b & 127, chunk = b >> 7;
            int iters = Kin >> 6;                 // {8,4,2}
            int slot = t >> 5, lane32 = t & 31, half = slot & 1;
            const float* bias = biasA[l];
            const float* pvec = pvA[l];
            float4 b4 = *(const float4*)(bias + lane32 * 4);
            float4 p4 = *(const float4*)(pvec + lane32 * 4);
            float qn0 = p4.x * p4.x + p4.y * p4.y + p4.z * p4.z + p4.w * p4.w;
            for (int it = 0; it < iters; ++it) {
                int idx = chunk * (Kin >> 2) + it * 16 + slot;
                int d = alive[g * Kin + idx];
                int jb = rp[d];
                int je = rp[d + 1];
                int deg = je - jb;

                int sid = 0; float wv = 0.f; bool livej = false;
                if (lane32 < deg) {
                    sid = csr[jb + lane32];
                    wv = dinv[sid];
                    livej = (wv != 0.f);
                }
                unsigned long long bal = __ballot(livej);
                unsigned hm = (unsigned)(bal >> (half * 32));
                int cnt = __popc(hm);
                if (livej) {
                    int pos = __popc(hm & ((1u << lane32) - 1));
                    s_nb[slot][pos] = make_float2(wv, __int_as_float(sid));
                }

                float dvd = dinv[d];
                float4 hd = *(const float4*)(h + (size_t)d * 128 + lane32 * 4);
                float4 a0, a1, a2, a3;
                a0.x = dvd * hd.x; a0.y = dvd * hd.y; a0.z = dvd * hd.z; a0.w = dvd * hd.w;
                a1 = make_float4(0.f, 0.f, 0.f, 0.f);
                a2 = a1; a3 = a1;

                int j = 0;
                for (; j + 4 <= cnt; j += 4) {
                    float2 n0 = s_nb[slot][j];
                    float2 n1 = s_nb[slot][j + 1];
                    float2 n2 = s_nb[slot][j + 2];
                    float2 n3 = s_nb[slot][j + 3];
                    float4 h0 = *(const float4*)(h + (size_t)__float_as_int(n0.y) * 128 + lane32 * 4);
                    float4 h1 = *(const float4*)(h + (size_t)__float_as_int(n1.y) * 128 + lane32 * 4);
                    float4 h2 = *(const float4*)(h + (size_t)__float_as_int(n2.y) * 128 + lane32 * 4);
                    float4 h3 = *(const float4*)(h + (size_t)__float_as_int(n3.y) * 128 + lane32 * 4);
                    a0.x = fmaf(n0.x, h0.x, a0.x); a0.y = fmaf(n0.x, h0.y, a0.y);
                    a0.z = fmaf(n0.x, h0.z, a0.z); a0.w = fmaf(n0.x, h0.w, a0.w);
                    a1.x = fmaf(n1.x, h1.x, a1.x); a1.y = fmaf(n1.x, h1.y, a1.y);
                    a1.z = fmaf(n1.x, h1.z, a1.z); a1.w = fmaf(n1.x, h1.w, a1.w);
                    a2.x = fmaf(n2.x, h2.x, a2.x); a2.y = fmaf(n2.x, h2.y, a2.y);
                    a2.z = fmaf(n2.x, h2.z, a2.z); a2.w = fmaf(n2.x, h2.w, a2.w);
                    a3.x = fmaf(n3.x, h3.x, a3.x); a3.y = fmaf(n3.x, h3.y, a3.y);
                    a3.z = fmaf(n3.x, h3.z, a3.z); a3.w = fmaf(n3.x, h3.w, a3.w);
                }
                for (; j < cnt; ++j) {
                    float2 n0 = s_nb[slot][j];
                    float4 h0 = *(const float4*)(h + (size_t)__float_as_int(n0.y) * 128 + lane32 * 4);
                    a0.x = fmaf(n0.x, h0.x, a0.x); a0.y = fmaf(n0.x, h0.y, a0.y);
                    a0.z = fmaf(n0.x, h0.z, a0.z); a0.w = fmaf(n0.x, h0.w, a0.w);
                }
                for (int j2 = jb + 32; j2 < je; ++j2) {
                    int s2 = csr[j2];
                    float w2 = dinv[s2];
                    float4 h2 = *(const float4*)(h + (size_t)s2 * 128 + lane32 * 4);
                    a0.x = fmaf(w2, h2.x, a0.x); a0.y = fmaf(w2, h2.y, a0.y);
                    a0.z = fmaf(w2, h2.z, a0.z); a0.w = fmaf(w2, h2.w, a0.w);
                }

                float4 o;
                o.x = fmaxf(fmaf(dvd, a0.x + a1.x + a2.x + a3.x, b4.x), 0.f);
                o.y = fmaxf(fmaf(dvd, a0.y + a1.y + a2.y + a3.y, b4.y), 0.f);
                o.z = fmaxf(fmaf(dvd, a0.z + a1.z + a2.z + a3.z, b4.z), 0.f);
                o.w = fmaxf(fmaf(dvd, a0.w + a1.w + a2.w + a3.w, b4.w), 0.f);

                _Float16 q0 = (_Float16)o.x, q1 = (_Float16)o.y, q2 = (_Float16)o.z, q3 = (_Float16)o.w;
                f16x4 oh = {q0, q1, q2, q3};
                f16x4 ol = {(_Float16)((o.x - (float)q0) * 2048.f), (_Float16)((o.y - (float)q1) * 2048.f),
                            (_Float16)((o.z - (float)q2) * 2048.f), (_Float16)((o.w - (float)q3) * 2048.f)};
                *(f16x4*)(xh + (size_t)d * 128 + lane32 * 4) = oh;
                *(f16x4*)(xl + (size_t)d * 128 + lane32 * 4) = ol;

                float ps = o.x * p4.x + o.y * p4.y + o.z * p4.z + o.w * p4.w;
                float qn = qn0;
                for (int m = 16; m >= 1; m >>= 1) {
                    ps += __shfl_xor(ps, m);
                    qn += __shfl_xor(qn, m);
                }
                if (lane32 == 0) score[d] = 1.f / (1.f + expf(-ps * rsqrtf(qn)));
            }
        }
        grid_sync(bar);

        // ---------- pool: radix-select top-K + readout + next dinv (b < 128) ----------
        if (b < NGRAPH) {
            int g = b;
            int K = KinA[l] >> 1;
            int gbase = g * NPG;
            int d = gbase + t;

            float odv = dinv[d];
            int m = odv > 0.f;
            float sc = score[d];
            unsigned bits = m ? __float_as_uint(sc) : 0u;
            unsigned bucket = bits >> 21;
            s_hist[t] = 0; s_hist[t + 512] = 0;
            if (t < 256) { s_ad[t] = gbase; s_ag[t] = 0.f; }
            if (t == 0) { s_scnt = 0; s_ccnt = 0; s_thr = -1e30f; s_tbb = 0; s_tbab = 0; }
            __syncthreads();
            atomicAdd(&s_hist[bucket], 1u);
            __syncthreads();
            unsigned a0 = s_hist[1023 - 2 * t];
            unsigned a1 = s_hist[1022 - 2 * t];
            unsigned pair = a0 + a1;
            unsigned v = pair;
            for (int o = 1; o < 64; o <<= 1) {
                unsigned n = __shfl_up(v, o);
                if ((t & 63) >= o) v += n;
            }
            if ((t & 63) == 63) s_wsum[t >> 6] = v;
            __syncthreads();
            if (t == 0) {
                unsigned run = 0;
                for (int i = 0; i < 8; ++i) { unsigned x = s_wsum[i]; s_wsum[i] = run; run += x; }
            }
            __syncthreads();
            unsigned incl = v + s_wsum[t >> 6];
            unsigned excl = incl - pair;
            unsigned uK = (unsigned)K;
            if (excl < uK && excl + a0 >= uK) { s_tbb = 1023 - 2 * t; s_tbab = excl; }
            else if (excl + a0 < uK && incl >= uK) { s_tbb = 1022 - 2 * t; s_tbab = excl + a0; }
            __syncthreads();
            unsigned bsel = s_tbb;
            unsigned r = uK - s_tbab;
            if (m && bucket == bsel) {
                unsigned pos = atomicAdd(&s_ccnt, 1u);
                s_cand[pos] = sc;
            }
            __syncthreads();
            unsigned c = s_ccnt;
            if (t < (int)c) {
                float vv = s_cand[t];
                unsigned gt = 0, eq = 0;
                for (unsigned i = 0; i < c; ++i) {
                    gt += (s_cand[i] > vv) ? 1u : 0u;
                    eq += (s_cand[i] == vv) ? 1u : 0u;
                }
                if (gt < r && gt + eq >= r) s_thr = vv;   // tie-robust
            }
            __syncthreads();
            float thr = s_thr;

            int nm = (m && sc >= thr) ? 1 : 0;
            gate[d] = nm ? sc : 0.f;
            s_mnew[t] = nm;
            if (nm) {
                int pos = atomicAdd(&s_scnt, 1);
                if (pos < K) {
                    alive[g * K + pos] = d;
                    s_ad[pos] = d;
                    s_ag[pos] = sc;
                }
            }
            __syncthreads();

            if (l != 2) {
                float nd = 0.f;
                if (nm) {
                    int jb = rp[d], je = rp[d + 1];
                    int sum = 0;
                    for (int j = jb; j < je; ++j) sum += s_mnew[csr[j] - gbase];
                    nd = rsqrtf(1.f + (float)sum);
                }
                dinv[d] = nd;
            }

            int f = t & 127, c2 = t >> 7;
            float mx = 0.f, sm = 0.f;
#define REC(node) ((float)xh[(size_t)(node) * 128 + f] + (float)xl[(size_t)(node) * 128 + f] * (1.f / 2048.f))
            for (int j = c2; j < K; j += 16) {
                float v0 = REC(s_ad[j]) * s_ag[j];
                float v1 = REC(s_ad[j + 4]) * s_ag[j + 4];
                float v2 = REC(s_ad[j + 8]) * s_ag[j + 8];
                float v3 = REC(s_ad[j + 12]) * s_ag[j + 12];
                mx = fmaxf(fmaxf(fmaxf(mx, v0), fmaxf(v1, v2)), v3);
                sm += v0 + v1 + v2 + v3;
            }
#undef REC
            s_red[t] = mx; s_red[512 + t] = sm;
            __syncthreads();
            if (c2 == 0) {
                for (int cc = 1; cc < 4; ++cc) {
                    mx = fmaxf(mx, s_red[cc * 128 + f]);
                    sm += s_red[512 + cc * 128 + f];
                }
                hg[g * 256 + f] += mx;
                hg[g * 256 + 128 + f] += sm / (float)K;
            }
        }
        grid_sync(bar);
    }

    // ---------- mlp head (b < 128) ----------
    if (b < NGRAPH) {
        int g = b;
        if (t < 64) {
            float a = 0.f;
            for (int j = 0; j < 64; ++j) a = fmaf(inp_c[g * 64 + j], We[j * 64 + t], a);
            s_fus[t] = fmaxf(a, 0.f);
        }
        if (t < 256) s_fus[64 + t] = hg[g * 256 + t];
        __syncthreads();
        if (t < 256) {
            float a = ba[t];
            for (int j = 0; j < 320; ++j) a = fmaf(s_fus[j], Wa[j * 256 + t], a);
            s_h1[t] = fmaxf(a, 0.f);
        }
        __syncthreads();
        if (t < 128) {
            float a = bb[t];
            for (int j = 0; j < 256; ++j) a = fmaf(s_h1[j], Wb[j * 128 + t], a);
            s_h2[t] = fmaxf(a, 0.f);
        }
        __syncthreads();
        if (t == 0) {
            float a = 0.f;
            for (int j = 0; j < 128; ++j) a = fmaf(s_h2[j], Wc[j], a);
            out[g] = a;
        }
    }
}

// ---------------- launch ----------------

extern "C" void kernel_launch(void* const* d_in, const int* in_sizes, int n_in,
                              void* d_out, int out_size, void* d_ws, size_t ws_size,
                              hipStream_t stream) {
    (void)in_sizes; (void)n_in; (void)out_size; (void)ws_size;
    const float* x_in  = (const float*)d_in[0];
    const float* inp_c = (const float*)d_in[1];
    const int*   ei    = (const int*)d_in[2];
    const int* srcE = ei;
    const int* dstE = ei + NEDGE;
    const float* W0 = (const float*)d_in[4];
    const float* b0 = (const float*)d_in[5];
    const float* W1 = (const float*)d_in[6];
    const float* b1 = (const float*)d_in[7];
    const float* W2 = (const float*)d_in[8];
    const float* b2 = (const float*)d_in[9];
    const float* p0 = (const float*)d_in[10];
    const float* p1 = (const float*)d_in[11];
    const float* p2 = (const float*)d_in[12];
    const float* We = (const float*)d_in[13];
    const float* Wa = (const float*)d_in[14];
    const float* ba = (const float*)d_in[15];
    const float* Wb = (const float*)d_in[16];
    const float* bb = (const float*)d_in[17];
    const float* Wc = (const float*)d_in[18];
    float* out = (float*)d_out;

    char* w = (char*)d_ws;
    size_t off = 0;
    auto alloc = [&](size_t bytes) -> void* {
        void* p = w + off;
        off = (off + bytes + 255) & ~(size_t)255;
        return p;
    };
    int*   rp    = (int*)alloc((NNODE + 1) * 4);
    int*   csr   = (int*)alloc(NEDGE * 4);
    float* dinv  = (float*)alloc(NNODE * 4);
    float* gate  = (float*)alloc(NNODE * 4);
    float* score = (float*)alloc(NNODE * 4);
    int*   alive = (int*)alloc(NNODE * 4);
    float* hbuf  = (float*)alloc((size_t)NNODE * 128 * 4);
    _Float16* xh = (_Float16*)alloc((size_t)NNODE * 128 * 2);
    _Float16* xl = (_Float16*)alloc((size_t)NNODE * 128 * 2);
    float* hg    = (float*)alloc(NGRAPH * 256 * 4);
    _Float16* wfh = (_Float16*)alloc(3 * 16384 * 2);
    _Float16* wfl = (_Float16*)alloc(3 * 16384 * 2);
    int* bar     = (int*)alloc(256);

    (void)hipMemsetAsync(bar, 0, 8, stream);
    k_mega<<<NBLK, 512, 0, stream>>>(x_in, inp_c, srcE, dstE,
                                     W0, W1, W2, b0, b1, b2, p0, p1, p2,
                                     We, Wa, ba, Wb, bb, Wc, out,
                                     rp, csr, dinv, gate, score, alive,
                                     hbuf, xh, xl, hg, wfh, wfl, bar);
}

// Round 10
// 343.844 us; speedup vs baseline: 4.7982x; 4.7982x over previous
//
#include <hip/hip_runtime.h>
#include <math.h>

#define NGRAPH 128
#define NPG 512
#define EPG 8192

typedef _Float16 f16x8 __attribute__((ext_vector_type(8)));
typedef _Float16 f16x4 __attribute__((ext_vector_type(4)));
typedef float f32x4 __attribute__((ext_vector_type(4)));

#define CVT8(hi8, lo8, a0, a1, a2, a3, a4, a5, a6, a7)                         \
    {                                                                           \
        _Float16 q0 = (_Float16)a0, q1 = (_Float16)a1, q2 = (_Float16)a2,       \
                 q3 = (_Float16)a3, q4 = (_Float16)a4, q5 = (_Float16)a5,       \
                 q6 = (_Float16)a6, q7 = (_Float16)a7;                          \
        hi8 = (f16x8){q0, q1, q2, q3, q4, q5, q6, q7};                          \
        lo8 = (f16x8){(_Float16)((a0 - (float)q0) * 2048.f),                    \
                      (_Float16)((a1 - (float)q1) * 2048.f),                    \
                      (_Float16)((a2 - (float)q2) * 2048.f),                    \
                      (_Float16)((a3 - (float)q3) * 2048.f),                    \
                      (_Float16)((a4 - (float)q4) * 2048.f),                    \
                      (_Float16)((a5 - (float)q5) * 2048.f),                    \
                      (_Float16)((a6 - (float)q6) * 2048.f),                    \
                      (_Float16)((a7 - (float)q7) * 2048.f)};                   \
    }

// One block per graph runs the ENTIRE network for that graph (everything is
// graph-local). Only __syncthreads() — no grid sync, no cross-XCD traffic.
__global__ __launch_bounds__(512, 2) void k_all(
    const float* __restrict__ x_in, const float* __restrict__ inp_c,
    const int* __restrict__ srcE, const int* __restrict__ dstE,
    const float* __restrict__ W0, const float* __restrict__ W1, const float* __restrict__ W2,
    const float* __restrict__ b0, const float* __restrict__ b1, const float* __restrict__ b2,
    const float* __restrict__ p0, const float* __restrict__ p1, const float* __restrict__ p2,
    const float* __restrict__ We, const float* __restrict__ Wa, const float* __restrict__ ba,
    const float* __restrict__ Wb, const float* __restrict__ bb, const float* __restrict__ Wc,
    float* __restrict__ out,
    unsigned short* __restrict__ csr16, float* __restrict__ hbuf,
    _Float16* __restrict__ xh, _Float16* __restrict__ xl) {

    __shared__ _Float16 wH[16384];   // 32 KB  W frags (hi), current layer
    __shared__ _Float16 wL[16384];   // 32 KB
    __shared__ _Float16 aH[9216];    // 18 KB  A staging 128 rows x 64k (+8 pad)
    __shared__ _Float16 aL[9216];    // 18 KB
    __shared__ float s_dinv[512];
    __shared__ float s_gate[512];
    __shared__ float s_score[512];
    __shared__ int s_alive[512];
    __shared__ int s_rp[513];
    __shared__ int s_cnt[512];
    __shared__ int s_tmp[512];
    __shared__ float2 s_nb[16][32];  // 4 KB
    __shared__ unsigned s_hist[1024];
    __shared__ unsigned s_wsum[8];
    __shared__ float s_cand[512];
    __shared__ float s_red[1024];
    __shared__ int s_ad[256];
    __shared__ float s_ag[256];
    __shared__ int s_mnew[512];
    __shared__ float s_hg[256];
    __shared__ int s_scnt;
    __shared__ unsigned s_ccnt, s_tbb, s_tbab;
    __shared__ float s_thr;
    __shared__ float s_fus[320];
    __shared__ float s_h1[256];
    __shared__ float s_h2[128];

    int g = blockIdx.x, t = threadIdx.x;
    const float* xg = x_in + (size_t)g * NPG * 128;
    unsigned short* csrg = csr16 + (size_t)g * EPG;
    float* hb = hbuf + (size_t)g * NPG * 128;
    _Float16* xhg = xh + (size_t)g * NPG * 128;
    _Float16* xlg = xl + (size_t)g * NPG * 128;

    // ---------- CSR build (local ids, ushort) + node-state init ----------
    s_cnt[t] = 0;
    s_gate[t] = 1.f;
    s_alive[t] = t;
    if (t < 256) s_hg[t] = 0.f;
    __syncthreads();
    {
        int ebase = g * EPG;
        int dl[16];
        for (int i = 0; i < 16; ++i) {
            int e = ebase + t + i * 512;
            int d = dstE[e] - g * NPG;
            dl[i] = d;
            atomicAdd(&s_cnt[d], 1);
        }
        __syncthreads();
        int v = s_cnt[t], incl = v;
        s_dinv[t] = rsqrtf(1.f + (float)v);   // layer-1 mask all ones
        for (int off = 1; off < 512; off <<= 1) {
            s_tmp[t] = incl; __syncthreads();
            if (t >= off) incl += s_tmp[t - off];
            __syncthreads();
        }
        s_rp[t] = incl - v;
        if (t == 511) s_rp[512] = EPG;
        __syncthreads();
        s_cnt[t] = s_rp[t];
        __syncthreads();
        for (int i = 0; i < 16; ++i) {
            int e = ebase + t + i * 512;
            int pos = atomicAdd(&s_cnt[dl[i]], 1);
            csrg[pos] = (unsigned short)(srcE[e] - g * NPG);
        }
    }

    const float* WA[3] = {W0, W1, W2};
    const float* bA[3] = {b0, b1, b2};
    const float* pA[3] = {p0, p1, p2};
    const int KinA[3] = {512, 256, 128};

    int lane = t & 63, wvi = t >> 6, quad = lane >> 4, mm = lane & 15;

    for (int l = 0; l < 3; ++l) {
        int Kin = KinA[l];
        __syncthreads();
        // ---- W -> LDS frags (hi/lo) ----
        {
            const float* W = WA[l];
            for (int i = 0; i < 32; ++i) {
                int e = t + i * 512;
                int k = e >> 7, n = e & 127;
                float w = W[e];
                _Float16 hi = (_Float16)w;
                _Float16 lo = (_Float16)((w - (float)hi) * 2048.f);
                int nt = n >> 4, nn = n & 15, ks = k >> 5, qd = (k & 31) >> 3, j = k & 7;
                int off = ((nt * 4 + ks) * 64 + (qd * 16 + nn)) * 8 + j;
                wH[off] = hi;
                wL[off] = lo;
            }
        }
        __syncthreads();

        // ---- GEMM: h[lid] = gate[lid] * (x[lid] @ W), split-f16 3-pass MFMA ----
        int ntile = Kin >> 7;
        for (int tt = 0; tt < ntile; ++tt) {
            f32x4 accH[8], accM[8];
            for (int nt = 0; nt < 8; ++nt) {
                accH[nt] = (f32x4){0.f, 0.f, 0.f, 0.f};
                accM[nt] = (f32x4){0.f, 0.f, 0.f, 0.f};
            }
            for (int kh = 0; kh < 2; ++kh) {
                __syncthreads();   // aH/aL reuse guard
                for (int pp = 0; pp < 2; ++pp) {
                    int c = t + pp * 512;
                    int r = c >> 3, ch = c & 7;
                    int lid = s_alive[tt * 128 + r];
                    f16x8 hi8, lo8;
                    if (l == 0) {
                        const float* src = xg + (size_t)lid * 128 + kh * 64 + ch * 8;
                        float4 v0 = *(const float4*)(src);
                        float4 v1 = *(const float4*)(src + 4);
                        CVT8(hi8, lo8, v0.x, v0.y, v0.z, v0.w, v1.x, v1.y, v1.z, v1.w);
                    } else {
                        hi8 = *(const f16x8*)(xhg + (size_t)lid * 128 + kh * 64 + ch * 8);
                        lo8 = *(const f16x8*)(xlg + (size_t)lid * 128 + kh * 64 + ch * 8);
                    }
                    *(f16x8*)(aH + r * 72 + ch * 8) = hi8;
                    *(f16x8*)(aL + r * 72 + ch * 8) = lo8;
                }
                __syncthreads();
                for (int ksl = 0; ksl < 2; ++ksl) {
                    int row = wvi * 16 + mm;
                    f16x8 Ah = *(const f16x8*)(aH + row * 72 + ksl * 32 + quad * 8);
                    f16x8 Al = *(const f16x8*)(aL + row * 72 + ksl * 32 + quad * 8);
                    for (int nt = 0; nt < 8; ++nt) {
                        f16x8 Bh = *(const f16x8*)(wH + ((nt * 4 + kh * 2 + ksl) * 64 + lane) * 8);
                        f16x8 Bl = *(const f16x8*)(wL + ((nt * 4 + kh * 2 + ksl) * 64 + lane) * 8);
                        accH[nt] = __builtin_amdgcn_mfma_f32_16x16x32_f16(Ah, Bh, accH[nt], 0, 0, 0);
                        accM[nt] = __builtin_amdgcn_mfma_f32_16x16x32_f16(Ah, Bl, accM[nt], 0, 0, 0);
                        accM[nt] = __builtin_amdgcn_mfma_f32_16x16x32_f16(Al, Bh, accM[nt], 0, 0, 0);
                    }
                }
            }
            // epilogue: C col=lane&15, row=quad*4+reg
            for (int i = 0; i < 4; ++i) {
                int lid = s_alive[tt * 128 + wvi * 16 + quad * 4 + i];
                float gg = s_gate[lid];
                float* hr = hb + (size_t)lid * 128 + mm;
                for (int nt = 0; nt < 8; ++nt)
                    hr[nt * 16] = gg * (accH[nt][i] + accM[nt][i] * (1.f / 2048.f));
            }
        }
        __syncthreads();   // h complete (stays in this CU's XCD L2)

        // ---- AGG + relu + score: half-wave per dst, 32-slot compacted prefetch ----
        {
            int slot = t >> 5, lane32 = t & 31, half = slot & 1;
            const float* bias = bA[l];
            const float* pvec = pA[l];
            float4 b4 = *(const float4*)(bias + lane32 * 4);
            float4 p4 = *(const float4*)(pvec + lane32 * 4);
            float qn0 = p4.x * p4.x + p4.y * p4.y + p4.z * p4.z + p4.w * p4.w;
            int iters = Kin >> 4;
            for (int it = 0; it < iters; ++it) {
                int lid = s_alive[it * 16 + slot];
                int jb = s_rp[lid], je = s_rp[lid + 1];
                int deg = je - jb;

                int sid = 0; float wvt = 0.f; bool livej = false;
                if (lane32 < deg) {
                    sid = csrg[jb + lane32];
                    wvt = s_dinv[sid];
                    livej = (wvt != 0.f);
                }
                unsigned long long bal = __ballot(livej);
                unsigned hm = (unsigned)(bal >> (half * 32));
                int cnt = __popc(hm);
                if (livej) {
                    int pos = __popc(hm & ((1u << lane32) - 1));
                    s_nb[slot][pos] = make_float2(wvt, __int_as_float(sid));
                }

                float dvd = s_dinv[lid];
                float4 hd = *(const float4*)(hb + (size_t)lid * 128 + lane32 * 4);
                float4 a0, a1, a2, a3;
                a0.x = dvd * hd.x; a0.y = dvd * hd.y; a0.z = dvd * hd.z; a0.w = dvd * hd.w;
                a1 = make_float4(0.f, 0.f, 0.f, 0.f);
                a2 = a1; a3 = a1;

                int j = 0;
                for (; j + 4 <= cnt; j += 4) {
                    float2 n0 = s_nb[slot][j];
                    float2 n1 = s_nb[slot][j + 1];
                    float2 n2 = s_nb[slot][j + 2];
                    float2 n3 = s_nb[slot][j + 3];
                    float4 h0 = *(const float4*)(hb + (size_t)__float_as_int(n0.y) * 128 + lane32 * 4);
                    float4 h1 = *(const float4*)(hb + (size_t)__float_as_int(n1.y) * 128 + lane32 * 4);
                    float4 h2 = *(const float4*)(hb + (size_t)__float_as_int(n2.y) * 128 + lane32 * 4);
                    float4 h3 = *(const float4*)(hb + (size_t)__float_as_int(n3.y) * 128 + lane32 * 4);
                    a0.x = fmaf(n0.x, h0.x, a0.x); a0.y = fmaf(n0.x, h0.y, a0.y);
                    a0.z = fmaf(n0.x, h0.z, a0.z); a0.w = fmaf(n0.x, h0.w, a0.w);
                    a1.x = fmaf(n1.x, h1.x, a1.x); a1.y = fmaf(n1.x, h1.y, a1.y);
                    a1.z = fmaf(n1.x, h1.z, a1.z); a1.w = fmaf(n1.x, h1.w, a1.w);
                    a2.x = fmaf(n2.x, h2.x, a2.x); a2.y = fmaf(n2.x, h2.y, a2.y);
                    a2.z = fmaf(n2.x, h2.z, a2.z); a2.w = fmaf(n2.x, h2.w, a2.w);
                    a3.x = fmaf(n3.x, h3.x, a3.x); a3.y = fmaf(n3.x, h3.y, a3.y);
                    a3.z = fmaf(n3.x, h3.z, a3.z); a3.w = fmaf(n3.x, h3.w, a3.w);
                }
                for (; j < cnt; ++j) {
                    float2 n0 = s_nb[slot][j];
                    float4 h0 = *(const float4*)(hb + (size_t)__float_as_int(n0.y) * 128 + lane32 * 4);
                    a0.x = fmaf(n0.x, h0.x, a0.x); a0.y = fmaf(n0.x, h0.y, a0.y);
                    a0.z = fmaf(n0.x, h0.z, a0.z); a0.w = fmaf(n0.x, h0.w, a0.w);
                }
                for (int j2 = jb + 32; j2 < je; ++j2) {   // deg>32 tail (~1e-4)
                    int s2 = csrg[j2];
                    float w2 = s_dinv[s2];
                    float4 h2 = *(const float4*)(hb + (size_t)s2 * 128 + lane32 * 4);
                    a0.x = fmaf(w2, h2.x, a0.x); a0.y = fmaf(w2, h2.y, a0.y);
                    a0.z = fmaf(w2, h2.z, a0.z); a0.w = fmaf(w2, h2.w, a0.w);
                }

                float4 o;
                o.x = fmaxf(fmaf(dvd, a0.x + a1.x + a2.x + a3.x, b4.x), 0.f);
                o.y = fmaxf(fmaf(dvd, a0.y + a1.y + a2.y + a3.y, b4.y), 0.f);
                o.z = fmaxf(fmaf(dvd, a0.z + a1.z + a2.z + a3.z, b4.z), 0.f);
                o.w = fmaxf(fmaf(dvd, a0.w + a1.w + a2.w + a3.w, b4.w), 0.f);

                _Float16 q0 = (_Float16)o.x, q1 = (_Float16)o.y, q2 = (_Float16)o.z, q3 = (_Float16)o.w;
                f16x4 oh = {q0, q1, q2, q3};
                f16x4 ol = {(_Float16)((o.x - (float)q0) * 2048.f), (_Float16)((o.y - (float)q1) * 2048.f),
                            (_Float16)((o.z - (float)q2) * 2048.f), (_Float16)((o.w - (float)q3) * 2048.f)};
                union { f16x4 v; unsigned long long u; } ch_, cl_;
                ch_.v = oh; cl_.v = ol;
                // non-temporal: keep h hot in L2 (x planes re-read later via L3)
                __builtin_nontemporal_store(ch_.u, (unsigned long long*)(xhg + (size_t)lid * 128 + lane32 * 4));
                __builtin_nontemporal_store(cl_.u, (unsigned long long*)(xlg + (size_t)lid * 128 + lane32 * 4));

                float ps = o.x * p4.x + o.y * p4.y + o.z * p4.z + o.w * p4.w;
                float qn = qn0;
                for (int m = 16; m >= 1; m >>= 1) {
                    ps += __shfl_xor(ps, m);
                    qn += __shfl_xor(qn, m);
                }
                if (lane32 == 0) s_score[lid] = 1.f / (1.f + expf(-ps * rsqrtf(qn)));
            }
        }
        __syncthreads();

        // ---- POOL: radix-select top-K + readout + next dinv ----
        {
            int K = Kin >> 1;
            float odv = s_dinv[t];
            int m = odv > 0.f;
            float sc = s_score[t];
            unsigned bits = m ? __float_as_uint(sc) : 0u;
            unsigned bucket = bits >> 21;
            s_hist[t] = 0; s_hist[t + 512] = 0;
            if (t < 256) { s_ad[t] = 0; s_ag[t] = 0.f; }
            if (t == 0) { s_scnt = 0; s_ccnt = 0; s_thr = -1e30f; s_tbb = 0; s_tbab = 0; }
            __syncthreads();
            atomicAdd(&s_hist[bucket], 1u);
            __syncthreads();
            unsigned a0h = s_hist[1023 - 2 * t];
            unsigned a1h = s_hist[1022 - 2 * t];
            unsigned pairh = a0h + a1h;
            unsigned v = pairh;
            for (int o = 1; o < 64; o <<= 1) {
                unsigned n = __shfl_up(v, o);
                if ((t & 63) >= o) v += n;
            }
            if ((t & 63) == 63) s_wsum[t >> 6] = v;
            __syncthreads();
            if (t == 0) {
                unsigned run = 0;
                for (int i = 0; i < 8; ++i) { unsigned x = s_wsum[i]; s_wsum[i] = run; run += x; }
            }
            __syncthreads();
            unsigned incl = v + s_wsum[t >> 6];
            unsigned excl = incl - pairh;
            unsigned uK = (unsigned)K;
            if (excl < uK && excl + a0h >= uK) { s_tbb = 1023 - 2 * t; s_tbab = excl; }
            else if (excl + a0h < uK && incl >= uK) { s_tbb = 1022 - 2 * t; s_tbab = excl + a0h; }
            __syncthreads();
            unsigned bsel = s_tbb;
            unsigned r = uK - s_tbab;
            if (m && bucket == bsel) {
                unsigned pos = atomicAdd(&s_ccnt, 1u);
                s_cand[pos] = sc;
            }
            __syncthreads();
            unsigned c = s_ccnt;
            if (t < (int)c) {
                float vv = s_cand[t];
                unsigned gt = 0, eq = 0;
                for (unsigned i = 0; i < c; ++i) {
                    gt += (s_cand[i] > vv) ? 1u : 0u;
                    eq += (s_cand[i] == vv) ? 1u : 0u;
                }
                if (gt < r && gt + eq >= r) s_thr = vv;   // tie-robust
            }
            __syncthreads();
            float thr = s_thr;

            int nm = (m && sc >= thr) ? 1 : 0;
            s_gate[t] = nm ? sc : 0.f;
            s_mnew[t] = nm;
            if (nm) {
                int pos = atomicAdd(&s_scnt, 1);
                if (pos < K) {
                    s_alive[pos] = t;
                    s_ad[pos] = t;
                    s_ag[pos] = sc;
                }
            }
            __syncthreads();

            if (l != 2) {
                float nd = 0.f;
                if (nm) {
                    int jb = s_rp[t], je = s_rp[t + 1];
                    int sum = 0;
                    for (int j = jb; j < je; ++j) sum += s_mnew[csrg[j]];
                    nd = rsqrtf(1.f + (float)sum);
                }
                s_dinv[t] = nd;
            }

            int f = t & 127, c2 = t >> 7;
            float mx = 0.f, sm = 0.f;
#define REC(lid) ((float)xhg[(size_t)(lid) * 128 + f] + (float)xlg[(size_t)(lid) * 128 + f] * (1.f / 2048.f))
            for (int j = c2; j < K; j += 16) {
                float v0 = REC(s_ad[j]) * s_ag[j];
                float v1 = REC(s_ad[j + 4]) * s_ag[j + 4];
                float v2 = REC(s_ad[j + 8]) * s_ag[j + 8];
                float v3 = REC(s_ad[j + 12]) * s_ag[j + 12];
                mx = fmaxf(fmaxf(fmaxf(mx, v0), fmaxf(v1, v2)), v3);
                sm += v0 + v1 + v2 + v3;
            }
#undef REC
            s_red[t] = mx; s_red[512 + t] = sm;
            __syncthreads();
            if (c2 == 0) {
                for (int cc = 1; cc < 4; ++cc) {
                    mx = fmaxf(mx, s_red[cc * 128 + f]);
                    sm += s_red[512 + cc * 128 + f];
                }
                s_hg[f] += mx;
                s_hg[128 + f] += sm / (float)K;
            }
        }
    }

    __syncthreads();
    // ---- MLP head ----
    if (t < 64) {
        float a = 0.f;
        for (int j = 0; j < 64; ++j) a = fmaf(inp_c[g * 64 + j], We[j * 64 + t], a);
        s_fus[t] = fmaxf(a, 0.f);
    }
    if (t < 256) s_fus[64 + t] = s_hg[t];
    __syncthreads();
    if (t < 256) {
        float a = ba[t];
        for (int j = 0; j < 320; ++j) a = fmaf(s_fus[j], Wa[j * 256 + t], a);
        s_h1[t] = fmaxf(a, 0.f);
    }
    __syncthreads();
    if (t < 128) {
        float a = bb[t];
        for (int j = 0; j < 256; ++j) a = fmaf(s_h1[j], Wb[j * 128 + t], a);
        s_h2[t] = fmaxf(a, 0.f);
    }
    __syncthreads();
    if (t == 0) {
        float a = 0.f;
        for (int j = 0; j < 128; ++j) a = fmaf(s_h2[j], Wc[j], a);
        out[g] = a;
    }
}

// ---------------- launch ----------------

extern "C" void kernel_launch(void* const* d_in, const int* in_sizes, int n_in,
                              void* d_out, int out_size, void* d_ws, size_t ws_size,
                              hipStream_t stream) {
    (void)in_sizes; (void)n_in; (void)out_size; (void)ws_size;
    const float* x_in  = (const float*)d_in[0];
    const float* inp_c = (const float*)d_in[1];
    const int*   ei    = (const int*)d_in[2];
    const int* srcE = ei;
    const int* dstE = ei + NGRAPH * EPG;
    const float* W0 = (const float*)d_in[4];
    const float* b0 = (const float*)d_in[5];
    const float* W1 = (const float*)d_in[6];
    const float* b1 = (const float*)d_in[7];
    const float* W2 = (const float*)d_in[8];
    const float* b2 = (const float*)d_in[9];
    const float* p0 = (const float*)d_in[10];
    const float* p1 = (const float*)d_in[11];
    const float* p2 = (const float*)d_in[12];
    const float* We = (const float*)d_in[13];
    const float* Wa = (const float*)d_in[14];
    const float* ba = (const float*)d_in[15];
    const float* Wb = (const float*)d_in[16];
    const float* bb = (const float*)d_in[17];
    const float* Wc = (const float*)d_in[18];
    float* out = (float*)d_out;

    char* w = (char*)d_ws;
    size_t off = 0;
    auto alloc = [&](size_t bytes) -> void* {
        void* p = w + off;
        off = (off + bytes + 255) & ~(size_t)255;
        return p;
    };
    unsigned short* csr16 = (unsigned short*)alloc((size_t)NGRAPH * EPG * 2);
    float* hbuf = (float*)alloc((size_t)NGRAPH * NPG * 128 * 4);
    _Float16* xh = (_Float16*)alloc((size_t)NGRAPH * NPG * 128 * 2);
    _Float16* xl = (_Float16*)alloc((size_t)NGRAPH * NPG * 128 * 2);

    k_all<<<NGRAPH, 512, 0, stream>>>(x_in, inp_c, srcE, dstE,
                                      W0, W1, W2, b0, b1, b2, p0, p1, p2,
                                      We, Wa, ba, Wb, bb, Wc, out,
                                      csr16, hbuf, xh, xl);
}

// Round 11
// 337.483 us; speedup vs baseline: 4.8887x; 1.0188x over previous
//
#include <hip/hip_runtime.h>
#include <math.h>

#define NGRAPH 128
#define NPG 512
#define EPG 8192

typedef _Float16 f16x8 __attribute__((ext_vector_type(8)));
typedef _Float16 f16x4 __attribute__((ext_vector_type(4)));
typedef float f32x4 __attribute__((ext_vector_type(4)));

// ---- CSR build (block per graph): local-id ushort csr, local rp, init node state ----

__global__ __launch_bounds__(512) void k_csr(const int* __restrict__ srcE, const int* __restrict__ dstE,
                                             int* __restrict__ rp, unsigned short* __restrict__ csr16,
                                             float* __restrict__ gate, int* __restrict__ alive,
                                             float* __restrict__ dinv) {
    __shared__ int cnt[512];
    __shared__ int tmp[512];
    int g = blockIdx.x, t = threadIdx.x;
    int nd = g * NPG + t;
    cnt[t] = 0;
    gate[nd] = 1.f;
    alive[nd] = nd;
    __syncthreads();
    int ebase = g * EPG;
    int dl[16];
    for (int i = 0; i < 16; ++i) {
        int e = ebase + t + i * 512;
        int d = dstE[e] - g * NPG;
        dl[i] = d;
        atomicAdd(&cnt[d], 1);
    }
    __syncthreads();
    int v = cnt[t], incl = v;
    dinv[nd] = rsqrtf(1.f + (float)v);   // layer-1: all masks = 1
    for (int off = 1; off < 512; off <<= 1) {
        tmp[t] = incl; __syncthreads();
        if (t >= off) incl += tmp[t - off];
        __syncthreads();
    }
    int excl = incl - v;
    rp[g * 513 + t] = excl;
    if (t == 511) rp[g * 513 + 512] = EPG;
    __syncthreads();
    cnt[t] = excl;
    __syncthreads();
    for (int i = 0; i < 16; ++i) {
        int e = ebase + t + i * 512;
        int pos = atomicAdd(&cnt[dl[i]], 1);
        csr16[(size_t)g * EPG + pos] = (unsigned short)(srcE[e] - g * NPG);
    }
}

#define CVT8(hi8, lo8, a0, a1, a2, a3, a4, a5, a6, a7)                         \
    {                                                                           \
        _Float16 q0 = (_Float16)a0, q1 = (_Float16)a1, q2 = (_Float16)a2,       \
                 q3 = (_Float16)a3, q4 = (_Float16)a4, q5 = (_Float16)a5,       \
                 q6 = (_Float16)a6, q7 = (_Float16)a7;                          \
        hi8 = (f16x8){q0, q1, q2, q3, q4, q5, q6, q7};                          \
        lo8 = (f16x8){(_Float16)((a0 - (float)q0) * 2048.f),                    \
                      (_Float16)((a1 - (float)q1) * 2048.f),                    \
                      (_Float16)((a2 - (float)q2) * 2048.f),                    \
                      (_Float16)((a3 - (float)q3) * 2048.f),                    \
                      (_Float16)((a4 - (float)q4) * 2048.f),                    \
                      (_Float16)((a5 - (float)q5) * 2048.f),                    \
                      (_Float16)((a6 - (float)q6) * 2048.f),                    \
                      (_Float16)((a7 - (float)q7) * 2048.f)};                   \
    }

// ---- fused layer: gemm (split-f16 MFMA) + agg + relu + partial score ----
// Block = (feature-quarter q, graph g), bid = q*128+g  =>  bid%8 == g%8: all blocks of a
// graph (all layers, all dispatches) pin to one XCD; h/xh/xl quarter stays in that L2.
// Agg is feature-separable: this block gathers ONLY its own h-quarter. No cross-block deps.

__global__ __launch_bounds__(512, 4) void k_layer(
    int l, int Kin, int ntile,
    const float* __restrict__ x_in, _Float16* __restrict__ xh, _Float16* __restrict__ xl,
    const float* __restrict__ W, const float* __restrict__ bias, const float* __restrict__ pvec,
    const float* __restrict__ gate, const int* __restrict__ alive, const float* __restrict__ dinv,
    const int* __restrict__ rp, const unsigned short* __restrict__ csr16,
    float* __restrict__ h, float* __restrict__ score_acc) {

    __shared__ _Float16 aH[9216];        // 18 KB: 128 rows x 64k (+8 pad)
    __shared__ _Float16 aL[9216];        // 18 KB
    __shared__ _Float16 wHl[4096];       // 8 KB: quarter W frags hi (2 nt x 4 ks x 64 x 8)
    __shared__ _Float16 wLl[4096];       // 8 KB
    __shared__ unsigned short s_csr[8192];  // 16 KB
    __shared__ int s_rp[513];
    __shared__ int s_alive[512];
    __shared__ float s_dinv[512];
    __shared__ float s_gate[512];

    int bid = blockIdx.x, t = threadIdx.x;
    int q = bid >> 7, g = bid & 127;
    int gbase = g * NPG;

    // ---- stage graph metadata into LDS ----
    {
        const uint4* csrc = (const uint4*)(csr16 + (size_t)g * EPG);
        uint4* cdst = (uint4*)s_csr;
        cdst[t] = csrc[t];
        cdst[t + 512] = csrc[t + 512];
        s_rp[t] = rp[g * 513 + t];
        if (t == 0) s_rp[512] = rp[g * 513 + 512];
        s_dinv[t] = dinv[gbase + t];
        s_gate[t] = gate[gbase + t];
        if (t < Kin) s_alive[t] = alive[g * Kin + t] - gbase;
        // W quarter -> LDS frags (hi/lo)
        for (int i = 0; i < 8; ++i) {
            int e = t + i * 512;             // 0..4095
            int k = e >> 5, nl = e & 31;
            float w = W[k * 128 + q * 32 + nl];
            _Float16 hi = (_Float16)w;
            _Float16 lo = (_Float16)((w - (float)hi) * 2048.f);
            int ntl = nl >> 4, nn = nl & 15, ks = k >> 5, qd = (k & 31) >> 3, j = k & 7;
            wHl[((ntl * 4 + ks) * 64 + qd * 16 + nn) * 8 + j] = hi;
            wLl[((ntl * 4 + ks) * 64 + qd * 16 + nn) * 8 + j] = lo;
        }
    }
    __syncthreads();

    int lane = t & 63, wvi = t >> 6, quad = lane >> 4, mm = lane & 15;
    float* hq = h + ((size_t)(q * 128 + g)) * NPG * 32;
    _Float16* xhq = xh + ((size_t)(q * 128 + g)) * NPG * 32;
    _Float16* xlq = xl + ((size_t)(q * 128 + g)) * NPG * 32;

    // ---- GEMM: hq[lid][0..32) = gate[lid] * (x_row @ W_quarter) ----
    for (int tt = 0; tt < ntile; ++tt) {
        f32x4 accH[2], accM[2];
        accH[0] = (f32x4){0.f, 0.f, 0.f, 0.f}; accH[1] = accH[0];
        accM[0] = accH[0]; accM[1] = accH[0];
        for (int kh = 0; kh < 2; ++kh) {
            __syncthreads();
            for (int pp = 0; pp < 2; ++pp) {
                int c = t + pp * 512;        // 0..1023: 128 rows x 8 chunks
                int r = c >> 3, ch = c & 7;
                int lid = s_alive[tt * 128 + r];
                f16x8 hi8, lo8;
                if (l == 0) {
                    const float* src = x_in + ((size_t)(gbase + lid)) * 128 + kh * 64 + ch * 8;
                    float4 v0 = *(const float4*)(src);
                    float4 v1 = *(const float4*)(src + 4);
                    CVT8(hi8, lo8, v0.x, v0.y, v0.z, v0.w, v1.x, v1.y, v1.z, v1.w);
                } else {
                    int k0 = kh * 64 + ch * 8;
                    int qs = k0 >> 5, c0 = k0 & 31;
                    size_t src = ((size_t)(qs * 128 + g) * NPG + lid) * 32 + c0;
                    hi8 = *(const f16x8*)(xh + src);
                    lo8 = *(const f16x8*)(xl + src);
                }
                *(f16x8*)(aH + r * 72 + ch * 8) = hi8;
                *(f16x8*)(aL + r * 72 + ch * 8) = lo8;
            }
            __syncthreads();
            for (int ksl = 0; ksl < 2; ++ksl) {
                int row = wvi * 16 + mm;
                f16x8 Ah = *(const f16x8*)(aH + row * 72 + ksl * 32 + quad * 8);
                f16x8 Al = *(const f16x8*)(aL + row * 72 + ksl * 32 + quad * 8);
                for (int nt = 0; nt < 2; ++nt) {
                    f16x8 Bh = *(const f16x8*)(wHl + ((nt * 4 + kh * 2 + ksl) * 64 + lane) * 8);
                    f16x8 Bl = *(const f16x8*)(wLl + ((nt * 4 + kh * 2 + ksl) * 64 + lane) * 8);
                    accH[nt] = __builtin_amdgcn_mfma_f32_16x16x32_f16(Ah, Bh, accH[nt], 0, 0, 0);
                    accM[nt] = __builtin_amdgcn_mfma_f32_16x16x32_f16(Ah, Bl, accM[nt], 0, 0, 0);
                    accM[nt] = __builtin_amdgcn_mfma_f32_16x16x32_f16(Al, Bh, accM[nt], 0, 0, 0);
                }
            }
        }
        // epilogue: C col=lane&15, row=quad*4+reg
        for (int i = 0; i < 4; ++i) {
            int lid = s_alive[tt * 128 + wvi * 16 + quad * 4 + i];
            float gg = s_gate[lid];
            float* hr = hq + (size_t)lid * 32 + mm;
            hr[0] = gg * (accH[0][i] + accM[0][i] * (1.f / 2048.f));
            hr[16] = gg * (accH[1][i] + accM[1][i] * (1.f / 2048.f));
        }
    }
    __syncthreads();   // this block's h-quarter complete (only this block reads it)

    // ---- AGG + relu + partial score: 8-lane group per dst, LDS csr/dinv, L2 h-gather ----
    {
        int grp = t >> 3, lane8 = t & 7;
        float4 b4 = *(const float4*)(bias + q * 32 + lane8 * 4);
        float4 p4 = *(const float4*)(pvec + q * 32 + lane8 * 4);
        int iters = Kin >> 6;
        for (int it = 0; it < iters; ++it) {
            int lid = s_alive[it * 64 + grp];
            int jb = s_rp[lid], je = s_rp[lid + 1];
            float dvd = s_dinv[lid];
            float4 hd = *(const float4*)(hq + (size_t)lid * 32 + lane8 * 4);
            float4 a0, a1;
            a0.x = dvd * hd.x; a0.y = dvd * hd.y; a0.z = dvd * hd.z; a0.w = dvd * hd.w;
            a1 = make_float4(0.f, 0.f, 0.f, 0.f);
            int j = jb;
            for (; j + 2 <= je; j += 2) {
                int s0 = s_csr[j], s1 = s_csr[j + 1];
                float w0 = s_dinv[s0], w1 = s_dinv[s1];
                if (w0 != 0.f) {
                    float4 h0 = *(const float4*)(hq + (size_t)s0 * 32 + lane8 * 4);
                    a0.x = fmaf(w0, h0.x, a0.x); a0.y = fmaf(w0, h0.y, a0.y);
                    a0.z = fmaf(w0, h0.z, a0.z); a0.w = fmaf(w0, h0.w, a0.w);
                }
                if (w1 != 0.f) {
                    float4 h1 = *(const float4*)(hq + (size_t)s1 * 32 + lane8 * 4);
                    a1.x = fmaf(w1, h1.x, a1.x); a1.y = fmaf(w1, h1.y, a1.y);
                    a1.z = fmaf(w1, h1.z, a1.z); a1.w = fmaf(w1, h1.w, a1.w);
                }
            }
            if (j < je) {
                int s0 = s_csr[j];
                float w0 = s_dinv[s0];
                if (w0 != 0.f) {
                    float4 h0 = *(const float4*)(hq + (size_t)s0 * 32 + lane8 * 4);
                    a0.x = fmaf(w0, h0.x, a0.x); a0.y = fmaf(w0, h0.y, a0.y);
                    a0.z = fmaf(w0, h0.z, a0.z); a0.w = fmaf(w0, h0.w, a0.w);
                }
            }
            float4 o;
            o.x = fmaxf(fmaf(dvd, a0.x + a1.x, b4.x), 0.f);
            o.y = fmaxf(fmaf(dvd, a0.y + a1.y, b4.y), 0.f);
            o.z = fmaxf(fmaf(dvd, a0.z + a1.z, b4.z), 0.f);
            o.w = fmaxf(fmaf(dvd, a0.w + a1.w, b4.w), 0.f);

            _Float16 q0 = (_Float16)o.x, q1 = (_Float16)o.y, q2 = (_Float16)o.z, q3 = (_Float16)o.w;
            f16x4 oh = {q0, q1, q2, q3};
            f16x4 ol = {(_Float16)((o.x - (float)q0) * 2048.f), (_Float16)((o.y - (float)q1) * 2048.f),
                        (_Float16)((o.z - (float)q2) * 2048.f), (_Float16)((o.w - (float)q3) * 2048.f)};
            *(f16x4*)(xhq + (size_t)lid * 32 + lane8 * 4) = oh;
            *(f16x4*)(xlq + (size_t)lid * 32 + lane8 * 4) = ol;

            float ps = o.x * p4.x + o.y * p4.y + o.z * p4.z + o.w * p4.w;
            ps += __shfl_xor(ps, 1);
            ps += __shfl_xor(ps, 2);
            ps += __shfl_xor(ps, 4);
            if (lane8 == 0) atomicAdd(&score_acc[gbase + lid], ps);
        }
    }
}

// ---- pool: finalize score + radix-select top-K + readout + next dinv (+ head on last) ----

__global__ __launch_bounds__(512) void k_pool(
    int K, int last,
    const _Float16* __restrict__ xh, const _Float16* __restrict__ xl,
    float* __restrict__ score_acc, const float* __restrict__ pvec,
    float* __restrict__ gate, int* __restrict__ alive, float* __restrict__ hg,
    const int* __restrict__ rp, const unsigned short* __restrict__ csr16,
    float* __restrict__ dinv,
    const float* __restrict__ inp_c, const float* __restrict__ We,
    const float* __restrict__ Wa, const float* __restrict__ ba,
    const float* __restrict__ Wb, const float* __restrict__ bb,
    const float* __restrict__ Wc, float* __restrict__ out) {

    __shared__ unsigned s_hist[1024];
    __shared__ unsigned s_wsum[8];
    __shared__ float s_cand[512];
    __shared__ float s_red[1024];
    __shared__ int s_ad[256];
    __shared__ float s_ag[256];
    __shared__ int s_mnew[512];
    __shared__ float s_hgf[256];
    __shared__ int s_scnt;
    __shared__ unsigned s_ccnt, s_tbb, s_tbab;
    __shared__ float s_thr;
    __shared__ float s_fus[320];
    __shared__ float s_h1[256];
    __shared__ float s_h2[128];

    int t = threadIdx.x, g = blockIdx.x;
    int gbase = g * NPG;
    int d = gbase + t;

    // ||p||^2
    s_red[t] = (t < 128) ? pvec[t] * pvec[t] : 0.f;
    if (t < 256) { s_ad[t] = 0; s_ag[t] = 0.f; }
    if (t == 0) { s_scnt = 0; s_ccnt = 0; s_thr = -1e30f; s_tbb = 0; s_tbab = 0; }
    __syncthreads();
    for (int off = 256; off >= 1; off >>= 1) {
        if (t < off) s_red[t] += s_red[t + off];
        __syncthreads();
    }
    float rn = rsqrtf(s_red[0]);
    __syncthreads();

    float odv = dinv[d];
    int m = odv > 0.f;
    float z = score_acc[d];
    score_acc[d] = 0.f;   // reset for next layer's atomics
    float sc = 1.f / (1.f + expf(-z * rn));
    unsigned bits = m ? __float_as_uint(sc) : 0u;
    unsigned bucket = bits >> 21;
    s_hist[t] = 0; s_hist[t + 512] = 0;
    __syncthreads();
    atomicAdd(&s_hist[bucket], 1u);
    __syncthreads();
    unsigned a0h = s_hist[1023 - 2 * t];
    unsigned a1h = s_hist[1022 - 2 * t];
    unsigned pairh = a0h + a1h;
    unsigned v = pairh;
    for (int o = 1; o < 64; o <<= 1) {
        unsigned n = __shfl_up(v, o);
        if ((t & 63) >= o) v += n;
    }
    if ((t & 63) == 63) s_wsum[t >> 6] = v;
    __syncthreads();
    if (t == 0) {
        unsigned run = 0;
        for (int i = 0; i < 8; ++i) { unsigned x = s_wsum[i]; s_wsum[i] = run; run += x; }
    }
    __syncthreads();
    unsigned incl = v + s_wsum[t >> 6];
    unsigned excl = incl - pairh;
    unsigned uK = (unsigned)K;
    if (excl < uK && excl + a0h >= uK) { s_tbb = 1023 - 2 * t; s_tbab = excl; }
    else if (excl + a0h < uK && incl >= uK) { s_tbb = 1022 - 2 * t; s_tbab = excl + a0h; }
    __syncthreads();
    unsigned bsel = s_tbb;
    unsigned r = uK - s_tbab;
    if (m && bucket == bsel) {
        unsigned pos = atomicAdd(&s_ccnt, 1u);
        s_cand[pos] = sc;
    }
    __syncthreads();
    unsigned c = s_ccnt;
    if (t < (int)c) {
        float vv = s_cand[t];
        unsigned gt = 0, eq = 0;
        for (unsigned i = 0; i < c; ++i) {
            gt += (s_cand[i] > vv) ? 1u : 0u;
            eq += (s_cand[i] == vv) ? 1u : 0u;
        }
        if (gt < r && gt + eq >= r) s_thr = vv;   // tie-robust
    }
    __syncthreads();
    float thr = s_thr;

    int nm = (m && sc >= thr) ? 1 : 0;
    gate[d] = nm ? sc : 0.f;
    s_mnew[t] = nm;
    if (nm) {
        int pos = atomicAdd(&s_scnt, 1);
        if (pos < K) {
            alive[g * K + pos] = d;
            s_ad[pos] = t;     // local id
            s_ag[pos] = sc;
        }
    }
    __syncthreads();

    if (!last) {
        float nd = 0.f;
        if (nm) {
            int jb = rp[g * 513 + t], je = rp[g * 513 + t + 1];
            int sum = 0;
            for (int j = jb; j < je; ++j) sum += s_mnew[csr16[(size_t)g * EPG + j]];
            nd = rsqrtf(1.f + (float)sum);
        }
        dinv[d] = nd;
    }

    // readout on new alive set (quarter-blocked xh/xl layout)
    int f = t & 127, c2 = t >> 7;
    int fq = f >> 5, fc = f & 31;
    size_t qb = ((size_t)(fq * 128 + g)) * NPG * 32 + fc;
    float mx = 0.f, sm = 0.f;
#define REC(lid) ((float)xh[qb + (size_t)(lid) * 32] + (float)xl[qb + (size_t)(lid) * 32] * (1.f / 2048.f))
    for (int j = c2; j < K; j += 16) {
        float v0 = REC(s_ad[j]) * s_ag[j];
        float v1 = REC(s_ad[j + 4]) * s_ag[j + 4];
        float v2 = REC(s_ad[j + 8]) * s_ag[j + 8];
        float v3 = REC(s_ad[j + 12]) * s_ag[j + 12];
        mx = fmaxf(fmaxf(fmaxf(mx, v0), fmaxf(v1, v2)), v3);
        sm += v0 + v1 + v2 + v3;
    }
#undef REC
    s_red[t] = mx; s_red[512 + t] = sm;
    __syncthreads();
    if (c2 == 0) {
        for (int cc = 1; cc < 4; ++cc) {
            mx = fmaxf(mx, s_red[cc * 128 + f]);
            sm += s_red[512 + cc * 128 + f];
        }
        if (!last) {
            hg[g * 256 + f] += mx;
            hg[g * 256 + 128 + f] += sm / (float)K;
        } else {
            s_hgf[f] = hg[g * 256 + f] + mx;
            s_hgf[128 + f] = hg[g * 256 + 128 + f] + sm / (float)K;
        }
    }
    if (!last) return;

    __syncthreads();
    // ---- MLP head ----
    if (t < 64) {
        float a = 0.f;
        for (int j = 0; j < 64; ++j) a = fmaf(inp_c[g * 64 + j], We[j * 64 + t], a);
        s_fus[t] = fmaxf(a, 0.f);
    }
    if (t < 256) s_fus[64 + t] = s_hgf[t];
    __syncthreads();
    if (t < 256) {
        float a = ba[t];
        for (int j = 0; j < 320; ++j) a = fmaf(s_fus[j], Wa[j * 256 + t], a);
        s_h1[t] = fmaxf(a, 0.f);
    }
    __syncthreads();
    if (t < 128) {
        float a = bb[t];
        for (int j = 0; j < 256; ++j) a = fmaf(s_h1[j], Wb[j * 128 + t], a);
        s_h2[t] = fmaxf(a, 0.f);
    }
    __syncthreads();
    if (t == 0) {
        float a = 0.f;
        for (int j = 0; j < 128; ++j) a = fmaf(s_h2[j], Wc[j], a);
        out[g] = a;
    }
}

// ---------------- launch ----------------

extern "C" void kernel_launch(void* const* d_in, const int* in_sizes, int n_in,
                              void* d_out, int out_size, void* d_ws, size_t ws_size,
                              hipStream_t stream) {
    (void)in_sizes; (void)n_in; (void)out_size; (void)ws_size;
    const float* x_in  = (const float*)d_in[0];
    const float* inp_c = (const float*)d_in[1];
    const int*   ei    = (const int*)d_in[2];
    const int* srcE = ei;
    const int* dstE = ei + NGRAPH * EPG;
    const float* Wl[3] = {(const float*)d_in[4], (const float*)d_in[6], (const float*)d_in[8]};
    const float* bl[3] = {(const float*)d_in[5], (const float*)d_in[7], (const float*)d_in[9]};
    const float* Pl[3] = {(const float*)d_in[10], (const float*)d_in[11], (const float*)d_in[12]};
    const float* We = (const float*)d_in[13];
    const float* Wa = (const float*)d_in[14];
    const float* ba = (const float*)d_in[15];
    const float* Wb = (const float*)d_in[16];
    const float* bb = (const float*)d_in[17];
    const float* Wc = (const float*)d_in[18];
    float* out = (float*)d_out;

    char* w = (char*)d_ws;
    size_t off = 0;
    auto alloc = [&](size_t bytes) -> void* {
        void* p = w + off;
        off = (off + bytes + 255) & ~(size_t)255;
        return p;
    };
    int* rp = (int*)alloc((size_t)NGRAPH * 513 * 4);
    unsigned short* csr16 = (unsigned short*)alloc((size_t)NGRAPH * EPG * 2);
    float* dinv = (float*)alloc((size_t)NGRAPH * NPG * 4);
    float* gate = (float*)alloc((size_t)NGRAPH * NPG * 4);
    float* sacc = (float*)alloc((size_t)NGRAPH * NPG * 4);
    int* alive = (int*)alloc((size_t)NGRAPH * NPG * 4);
    float* hbuf = (float*)alloc((size_t)NGRAPH * NPG * 128 * 4);
    _Float16* xh = (_Float16*)alloc((size_t)NGRAPH * NPG * 128 * 2);
    _Float16* xl = (_Float16*)alloc((size_t)NGRAPH * NPG * 128 * 2);
    float* hg = (float*)alloc((size_t)NGRAPH * 256 * 4);

    (void)hipMemsetAsync(sacc, 0, (size_t)NGRAPH * NPG * 4, stream);
    (void)hipMemsetAsync(hg, 0, (size_t)NGRAPH * 256 * 4, stream);
    k_csr<<<NGRAPH, 512, 0, stream>>>(srcE, dstE, rp, csr16, gate, alive, dinv);

    const int KinA[3] = {512, 256, 128};
    for (int l = 0; l < 3; ++l) {
        k_layer<<<512, 512, 0, stream>>>(l, KinA[l], KinA[l] >> 7,
                                         x_in, xh, xl, Wl[l], bl[l], Pl[l],
                                         gate, alive, dinv, rp, csr16, hbuf, sacc);
        k_pool<<<NGRAPH, 512, 0, stream>>>(KinA[l] >> 1, l == 2,
                                           xh, xl, sacc, Pl[l], gate, alive, hg,
                                           rp, csr16, dinv,
                                           inp_c, We, Wa, ba, Wb, bb, Wc, out);
    }
}